// Round 13
// baseline (1754.795 us; speedup 1.0000x reference)
//
#include <hip/hip_runtime.h>
#include <hip/hip_bf16.h>

#define TT 2048
#define BB 512
#define HH 64
#define L2E 1.44269504088896340736f

typedef _Float16 h2 __attribute__((ext_vector_type(2)));

__device__ __forceinline__ float frcp(float x){ return __builtin_amdgcn_rcpf(x); }
__device__ __forceinline__ float fexp2(float x){ return __builtin_amdgcn_exp2f(x); }
__device__ __forceinline__ float fsig(float a){ return frcp(1.0f + __expf(-a)); }
__device__ __forceinline__ float ftanh(float a){ return 1.0f - 2.0f*frcp(__expf(2.0f*a)+1.0f); }
__device__ __forceinline__ h2 pk16(float lo, float hi){
  return __builtin_bit_cast(h2, __builtin_amdgcn_cvt_pkrtz(lo, hi));
}
__device__ __forceinline__ int pk16i(float lo, float hi){
  return __builtin_bit_cast(int, pk16(lo, hi));
}
__device__ __forceinline__ float dot2(int w, int hp, float acc){
  return __builtin_amdgcn_fdot2(__builtin_bit_cast(h2, w),
                                __builtin_bit_cast(h2, hp), acc, false);
}

// TWO batch rows per wave, interleaved in one instruction stream.
// R11 post-mortem: per-step wall ~993 cyc vs ~420 issue => ~60% serial-latency
// stall (h LDS round-trip, trans chain). A second independent row's issue
// fills those stalls. Weights are SHARED: all 4 gates' Whh live in LDS
// ([gate][kb][lane] int4 -> conflict-free ds_read_b128), read once per
// iteration and reused by both rows. 256 single-wave blocks = 1 wave/CU ->
// LDS pipe uncontended. x pre-packed to f16 pairs for both rows; h broadcast
// per row via the proven same-wave LDS round-trip, each row's round-trip
// latency covered by the other row's dot phase.
__global__ void __launch_bounds__(64)
__attribute__((amdgpu_waves_per_eu(1, 1)))
lstm_fwd_kernel(
    const float* __restrict__ x, const float* __restrict__ Wih,
    const float* __restrict__ Whh, const float* __restrict__ bih,
    const float* __restrict__ bhh, float* __restrict__ hout)
{
  const int b0 = blockIdx.x * 2;    // rows b0, b0+1
  const int l  = threadIdx.x;       // lane == hidden unit

  __shared__ int4 xsf[2][TT];       // x as f16 pairs, both rows: 64 KB
  __shared__ int4 wlds[4][8][HH];   // all Whh gates: [gate][kb][lane], 32 KB
  __shared__ int4 hlds[2][HH/8];    // h as f16[64] per row: 256 B

  // ---- one-time: stage x rows as packed f16 pairs ----
  #pragma unroll 1
  for (int r = 0; r < 2; ++r){
    const float* xr = x + (size_t)(b0 + r)*TT*7;
    #pragma unroll 1
    for (int it = 0; it < TT/64; ++it){
      const int t = it*64 + l;
      const float* p = xr + (size_t)t*7;
      int4 v;
      v.x = pk16i(p[0], p[1]);
      v.y = pk16i(p[2], p[3]);
      v.z = pk16i(p[4], p[5]);
      v.w = pk16i(p[6], 0.0f);
      xsf[r][t] = v;
    }
  }

  // ---- one-time: stage ALL recurrent weights into LDS (exp2 pre-scaled) ----
  #pragma unroll
  for (int q = 0; q < 4; ++q){
    const float sq = (q == 2) ? (-2.0f*L2E) : (-L2E);
    const float4* wr = reinterpret_cast<const float4*>(Whh + (size_t)(q*HH + l)*HH);
    #pragma unroll
    for (int kb = 0; kb < 8; ++kb){
      float4 a = wr[2*kb], b4 = wr[2*kb+1];
      int4 v;
      v.x = pk16i(a.x*sq,  a.y*sq);
      v.y = pk16i(a.z*sq,  a.w*sq);
      v.z = pk16i(b4.x*sq, b4.y*sq);
      v.w = pk16i(b4.z*sq, b4.w*sq);
      wlds[q][kb][l] = v;
    }
  }

  // ---- input-projection weights as f16 pairs + f32 bias (registers) ----
  int wi16[4][4];
  float bias[4];
  #pragma unroll
  for (int q = 0; q < 4; q++){
    const float sq = (q==2) ? (-2.0f*L2E) : (-L2E);
    const int g = q*HH + l;
    wi16[q][0] = pk16i(Wih[g*7+0]*sq, Wih[g*7+1]*sq);
    wi16[q][1] = pk16i(Wih[g*7+2]*sq, Wih[g*7+3]*sq);
    wi16[q][2] = pk16i(Wih[g*7+4]*sq, Wih[g*7+5]*sq);
    wi16[q][3] = pk16i(Wih[g*7+6]*sq, 0.0f);
    bias[q] = (bih[g] + bhh[g])*sq;
  }

  // h_0 = 0 for both rows (same-wave in-order DS makes this visible below)
  {
    int4* hf = &hlds[0][0];
    if (l < 16) hf[l] = int4{0,0,0,0};
  }

  float h0 = 0.0f, c0 = 0.0f, h1 = 0.0f, c1 = 0.0f;

  // prologue: first h-reads (zeros) + first x
  int hw0[32], hw1[32];
  #pragma unroll
  for (int i = 0; i < 8; i++){
    int4 v = hlds[0][i];
    hw0[4*i+0]=v.x; hw0[4*i+1]=v.y; hw0[4*i+2]=v.z; hw0[4*i+3]=v.w;
  }
  #pragma unroll
  for (int i = 0; i < 8; i++){
    int4 v = hlds[1][i];
    hw1[4*i+0]=v.x; hw1[4*i+1]=v.y; hw1[4*i+2]=v.z; hw1[4*i+3]=v.w;
  }
  int4 xv0 = xsf[0][0];
  int4 xv1 = xsf[1][0];

  #pragma unroll 1
  for (int t = 0; t < TT; ++t){
    float a00 = bias[0], a01 = bias[1], a02 = bias[2], a03 = bias[3];
    float a10 = bias[0], a11 = bias[1], a12 = bias[2], a13 = bias[3];

    // x-projection for both rows (x regs ready from last iteration; these
    // 32 dot2 cover the first W-gate read latency)
    a00 = dot2(wi16[0][0], xv0.x, a00); a00 = dot2(wi16[0][1], xv0.y, a00);
    a00 = dot2(wi16[0][2], xv0.z, a00); a00 = dot2(wi16[0][3], xv0.w, a00);
    a01 = dot2(wi16[1][0], xv0.x, a01); a01 = dot2(wi16[1][1], xv0.y, a01);
    a01 = dot2(wi16[1][2], xv0.z, a01); a01 = dot2(wi16[1][3], xv0.w, a01);
    a02 = dot2(wi16[2][0], xv0.x, a02); a02 = dot2(wi16[2][1], xv0.y, a02);
    a02 = dot2(wi16[2][2], xv0.z, a02); a02 = dot2(wi16[2][3], xv0.w, a02);
    a03 = dot2(wi16[3][0], xv0.x, a03); a03 = dot2(wi16[3][1], xv0.y, a03);
    a03 = dot2(wi16[3][2], xv0.z, a03); a03 = dot2(wi16[3][3], xv0.w, a03);

    a10 = dot2(wi16[0][0], xv1.x, a10); a10 = dot2(wi16[0][1], xv1.y, a10);
    a10 = dot2(wi16[0][2], xv1.z, a10); a10 = dot2(wi16[0][3], xv1.w, a10);
    a11 = dot2(wi16[1][0], xv1.x, a11); a11 = dot2(wi16[1][1], xv1.y, a11);
    a11 = dot2(wi16[1][2], xv1.z, a11); a11 = dot2(wi16[1][3], xv1.w, a11);
    a12 = dot2(wi16[2][0], xv1.x, a12); a12 = dot2(wi16[2][1], xv1.y, a12);
    a12 = dot2(wi16[2][2], xv1.z, a12); a12 = dot2(wi16[2][3], xv1.w, a12);
    a13 = dot2(wi16[3][0], xv1.x, a13); a13 = dot2(wi16[3][1], xv1.y, a13);
    a13 = dot2(wi16[3][2], xv1.z, a13); a13 = dot2(wi16[3][3], xv1.w, a13);

    // recurrent dots, gate-major; W read once per gate, used by BOTH rows.
    // 8 transient int4 W regs reused gate-to-gate (register window stays small)
    #pragma unroll
    for (int q = 0; q < 4; ++q){
      int4 w0 = wlds[q][0][l], w1 = wlds[q][1][l], w2 = wlds[q][2][l], w3 = wlds[q][3][l];
      int4 w4 = wlds[q][4][l], w5 = wlds[q][5][l], w6 = wlds[q][6][l], w7 = wlds[q][7][l];
      float s0, s1;
      s0 = (q==0)?a00:(q==1)?a01:(q==2)?a02:a03;
      s1 = (q==0)?a10:(q==1)?a11:(q==2)?a12:a13;
      #define QD(w_, kb) \
        s0 = dot2((w_).x, hw0[4*(kb)+0], s0); s0 = dot2((w_).y, hw0[4*(kb)+1], s0); \
        s0 = dot2((w_).z, hw0[4*(kb)+2], s0); s0 = dot2((w_).w, hw0[4*(kb)+3], s0); \
        s1 = dot2((w_).x, hw1[4*(kb)+0], s1); s1 = dot2((w_).y, hw1[4*(kb)+1], s1); \
        s1 = dot2((w_).z, hw1[4*(kb)+2], s1); s1 = dot2((w_).w, hw1[4*(kb)+3], s1);
      QD(w0,0) QD(w1,1) QD(w2,2) QD(w3,3) QD(w4,4) QD(w5,5) QD(w6,6) QD(w7,7)
      #undef QD
      if (q==0){ a00=s0; a10=s1; } else if (q==1){ a01=s0; a11=s1; }
      else if (q==2){ a02=s0; a12=s1; } else { a03=s0; a13=s1; }
    }

    // ---- finish row 0: activations, state, publish h0, re-read hw0 ----
    {
      const float e0 = fexp2(a00), e1 = fexp2(a01), e2 = fexp2(a02), e3 = fexp2(a03);
      const float iv = frcp(1.0f + e0);
      const float fv = frcp(1.0f + e1);
      const float gv = 2.0f*frcp(1.0f + e2) - 1.0f;
      const float ov = frcp(1.0f + e3);
      c0 = fv*c0 + iv*gv;
      const float r = frcp(1.0f + fexp2(c0*(-2.0f*L2E)));
      h0 = 2.0f*ov*r - ov;
      reinterpret_cast<unsigned short*>(&hlds[0][0])[l] =
          __builtin_bit_cast(unsigned short, (_Float16)h0);
      #pragma unroll
      for (int i = 0; i < 8; i++){
        int4 v = hlds[0][i];
        hw0[4*i+0]=v.x; hw0[4*i+1]=v.y; hw0[4*i+2]=v.z; hw0[4*i+3]=v.w;
      }
    }

    // ---- finish row 1 (covers row 0's h round-trip) ----
    {
      const float e0 = fexp2(a10), e1 = fexp2(a11), e2 = fexp2(a12), e3 = fexp2(a13);
      const float iv = frcp(1.0f + e0);
      const float fv = frcp(1.0f + e1);
      const float gv = 2.0f*frcp(1.0f + e2) - 1.0f;
      const float ov = frcp(1.0f + e3);
      c1 = fv*c1 + iv*gv;
      const float r = frcp(1.0f + fexp2(c1*(-2.0f*L2E)));
      h1 = 2.0f*ov*r - ov;
      reinterpret_cast<unsigned short*>(&hlds[1][0])[l] =
          __builtin_bit_cast(unsigned short, (_Float16)h1);
      #pragma unroll
      for (int i = 0; i < 8; i++){
        int4 v = hlds[1][i];
        hw1[4*i+0]=v.x; hw1[4*i+1]=v.y; hw1[4*i+2]=v.z; hw1[4*i+3]=v.w;
      }
    }

    // prefetch next step's x for both rows
    const int tn = (t+1) & (TT-1);
    xv0 = xsf[0][tn];
    xv1 = xsf[1][tn];
  }
  hout[(b0+0)*HH + l] = h0;
  hout[(b0+1)*HH + l] = h1;
}

// Backward direction contributes only ONE step (scan reverse=True: output at
// t=T-1 is the first reverse step from zero state => W_hh_b unused, c = i*g).
// Fused with the final linear layer.
__global__ __launch_bounds__(64, 1) void lstm_bwd_lin_kernel(
    const float* __restrict__ x,   const float* __restrict__ Wib,
    const float* __restrict__ bib, const float* __restrict__ bhb,
    const float* __restrict__ Wlin,const float* __restrict__ blin,
    const float* __restrict__ hf,  float* __restrict__ out)
{
  const int b = blockIdx.x;
  const int j = threadIdx.x;  // 0..63
  const float* xt = x + ((size_t)b*TT + (TT-1))*7;
  float xv[7];
  #pragma unroll
  for (int k = 0; k < 7; k++) xv[k] = xt[k];

  float g4[4];
  #pragma unroll
  for (int qq = 0; qq < 4; qq++){
    const int g = qq*HH + j;
    float a = bib[g] + bhb[g];
    #pragma unroll
    for (int k = 0; k < 7; k++) a += xv[k]*Wib[g*7+k];
    g4[qq] = a;
  }
  const float iv = fsig(g4[0]);
  const float gv = ftanh(g4[2]);
  const float ov = fsig(g4[3]);
  const float cc = iv*gv;          // f * c0 = 0
  const float hb = ov*ftanh(cc);
  const float hfv = hf[b*HH + j];

  float s[3];
  #pragma unroll
  for (int o = 0; o < 3; o++)
    s[o] = hfv*Wlin[o*128 + j] + hb*Wlin[o*128 + 64 + j];

  #pragma unroll
  for (int o = 0; o < 3; o++){
    float v = s[o];
    #pragma unroll
    for (int m = 32; m >= 1; m >>= 1) v += __shfl_xor(v, m, 64);
    s[o] = v;
  }
  if (j == 0){
    out[b*3+0] = s[0] + blin[0];
    out[b*3+1] = s[1] + blin[1];
    out[b*3+2] = s[2] + blin[2];
  }
}

extern "C" void kernel_launch(void* const* d_in, const int* in_sizes, int n_in,
                              void* d_out, int out_size, void* d_ws, size_t ws_size,
                              hipStream_t stream)
{
  const float* x    = (const float*)d_in[0];
  const float* Wihf = (const float*)d_in[1];
  const float* Whhf = (const float*)d_in[2];
  const float* bihf = (const float*)d_in[3];
  const float* bhhf = (const float*)d_in[4];
  const float* Wihb = (const float*)d_in[5];
  // d_in[6] (W_hh_b) is mathematically unused: backward state starts at zero
  const float* bibb = (const float*)d_in[7];
  const float* bhbb = (const float*)d_in[8];
  const float* Wlin = (const float*)d_in[9];
  const float* blin = (const float*)d_in[10];
  float* out = (float*)d_out;
  float* hf  = (float*)d_ws;   // [512,64] fp32 scratch

  lstm_fwd_kernel<<<BB/2, 64, 0, stream>>>(x, Wihf, Whhf, bihf, bhhf, hf);
  lstm_bwd_lin_kernel<<<BB, 64, 0, stream>>>(x, Wihb, bibb, bhbb, Wlin, blin, hf, out);
}

// Round 14
// 1468.982 us; speedup vs baseline: 1.1946x; 1.1946x over previous
//
#include <hip/hip_runtime.h>
#include <hip/hip_bf16.h>

#define TT 2048
#define BB 512
#define HH 64
#define L2E 1.44269504088896340736f

typedef _Float16 h2 __attribute__((ext_vector_type(2)));
typedef _Float16 f16x8 __attribute__((ext_vector_type(8)));
typedef float f32x4 __attribute__((ext_vector_type(4)));

__device__ __forceinline__ float frcp(float x){ return __builtin_amdgcn_rcpf(x); }
__device__ __forceinline__ float fexp2(float x){ return __builtin_amdgcn_exp2f(x); }
__device__ __forceinline__ float fsig(float a){ return frcp(1.0f + __expf(-a)); }
__device__ __forceinline__ float ftanh(float a){ return 1.0f - 2.0f*frcp(__expf(2.0f*a)+1.0f); }
__device__ __forceinline__ h2 pk16(float lo, float hi){
  return __builtin_bit_cast(h2, __builtin_amdgcn_cvt_pkrtz(lo, hi));
}
__device__ __forceinline__ int pk16i(float lo, float hi){
  return __builtin_bit_cast(int, pk16(lo, hi));
}

// MFMA formulation (R12 post-mortem: lane-parallel design is pinned at
// ~1000 cyc/step = VALU dots + DS weight reads + latency; every variant
// just trades between the two pipes). Here the dots move to the MATRIX pipe:
//   gates[256] = [h(64); x(7); 1; 0pad] (K=96) . W[96][256]
// as 16 N-tiles x 3 K-tiles of mfma_f32_16x16x32_f16. The A operand is read
// uniformly per 16-lane group (same 16B of h/x for all lanes in a group), so
// ALL 16 C rows are identical copies of the gate vector: lane l holds gate
// 16*nt + (l&15) in acc[nt][0]. Weights are loop-invariant MFMA B operands
// -> allocator parks them in AGPRs where MFMA reads them NATIVELY (the AGPR
// bounce that plagued R5-R10 becomes free). Per step: 3 ds_read_b128 +
// 4 ds_write_b16 (~60 DS cyc, was ~310) + ~95 VALU (act/state, was ~370)
// + 48 MFMA on the idle matrix pipe.
__global__ void __launch_bounds__(64)
__attribute__((amdgpu_waves_per_eu(1, 1)))
lstm_fwd_kernel(
    const float* __restrict__ x, const float* __restrict__ Wih,
    const float* __restrict__ Whh, const float* __restrict__ bih,
    const float* __restrict__ bhh, float* __restrict__ hout)
{
  const int b  = blockIdx.x;
  const int l  = threadIdx.x;
  const int ln = l & 15;          // N index within tile (gate col)
  const int kg = l >> 4;          // K group (8 f16 per group)

  __shared__ int4 xs[TT + 4];     // x packed f16: (x0,x1)(x2,x3)(x4,x5)(x6,1.0)
  __shared__ int4 hlds[10];       // h as f16[64] = 128B + pad

  // ---- one-time: stage x as packed f16 (+1.0 bias slot) ----
  #pragma unroll 1
  for (int it = 0; it < TT/64; ++it){
    const int t = it*64 + l;
    const float* p = x + ((size_t)b*TT + t)*7;
    int4 v;
    v.x = pk16i(p[0], p[1]);
    v.y = pk16i(p[2], p[3]);
    v.z = pk16i(p[4], p[5]);
    v.w = pk16i(p[6], 1.0f);
    xs[t] = v;
  }
  if (l < 4)  xs[TT + l] = int4{0,0,0,0};   // pad: kg>0 lanes read past xs[t]
  if (l < 10) hlds[l]    = int4{0,0,0,0};   // h_0 = 0

  // ---- B fragments (loop-invariant MFMA operands -> AGPR-resident) ----
  // b[nt][kt]: n = nt*16+ln, k = kt*32 + kg*8 .. +8.  kt=2: [Wih ; bias ; 0].
  // All pre-scaled by -log2e (g-gate rows by -2log2e) for exp2 activations.
  int4 bf[16][3];
  #pragma unroll
  for (int nt = 0; nt < 16; ++nt){
    const int n = nt*16 + ln;
    const float sq = ((n >> 6) == 2) ? (-2.0f*L2E) : (-L2E);
    const float* wr = Whh + (size_t)n*HH;
    #pragma unroll
    for (int kt = 0; kt < 2; ++kt){
      const int kb = kt*32 + kg*8;
      int4 v;
      v.x = pk16i(wr[kb+0]*sq, wr[kb+1]*sq);
      v.y = pk16i(wr[kb+2]*sq, wr[kb+3]*sq);
      v.z = pk16i(wr[kb+4]*sq, wr[kb+5]*sq);
      v.w = pk16i(wr[kb+6]*sq, wr[kb+7]*sq);
      bf[nt][kt] = v;
    }
    int4 v2 = int4{0,0,0,0};
    if (kg == 0){
      const float* wi = Wih + (size_t)n*7;
      v2.x = pk16i(wi[0]*sq, wi[1]*sq);
      v2.y = pk16i(wi[2]*sq, wi[3]*sq);
      v2.z = pk16i(wi[4]*sq, wi[5]*sq);
      v2.w = pk16i(wi[6]*sq, (bih[n] + bhh[n])*sq);
    }
    bf[nt][2] = v2;
  }

  float cst[4] = {0.f, 0.f, 0.f, 0.f};   // c for units 16j+ln
  const f32x4 zero4 = {0.f, 0.f, 0.f, 0.f};

  #pragma unroll 1
  for (int t = 0; t < TT; ++t){
    // A fragments: every lane in a kg-group reads the SAME 16B (broadcast).
    const int4 a0 = *reinterpret_cast<const int4*>(
        reinterpret_cast<const char*>(hlds) + kg*16);          // h k=0..31
    const int4 a1 = *reinterpret_cast<const int4*>(
        reinterpret_cast<const char*>(hlds) + 64 + kg*16);     // h k=32..63
    const int4 a2 = *reinterpret_cast<const int4*>(
        reinterpret_cast<const char*>(&xs[t]) + kg*16);        // x,1 (kg=0)

    f32x4 acc[16];
    #pragma unroll
    for (int nt = 0; nt < 16; ++nt)
      acc[nt] = __builtin_amdgcn_mfma_f32_16x16x32_f16(
          __builtin_bit_cast(f16x8, a0), __builtin_bit_cast(f16x8, bf[nt][0]),
          zero4, 0, 0, 0);
    #pragma unroll
    for (int nt = 0; nt < 16; ++nt)
      acc[nt] = __builtin_amdgcn_mfma_f32_16x16x32_f16(
          __builtin_bit_cast(f16x8, a1), __builtin_bit_cast(f16x8, bf[nt][1]),
          acc[nt], 0, 0, 0);
    #pragma unroll
    for (int nt = 0; nt < 16; ++nt)
      acc[nt] = __builtin_amdgcn_mfma_f32_16x16x32_f16(
          __builtin_bit_cast(f16x8, a2), __builtin_bit_cast(f16x8, bf[nt][2]),
          acc[nt], 0, 0, 0);

    // gate G = 16*nt + ln = q*64 + u  ->  q = nt>>2, u = 16*(nt&3) + ln.
    // i: nt 0..3, f: 4..7, g: 8..11, o: 12..15 (j = nt&3 = unit group).
    float hval[4];
    #pragma unroll
    for (int j = 0; j < 4; ++j){
      const float iv = frcp(1.0f + fexp2(acc[ 0+j][0]));
      const float fv = frcp(1.0f + fexp2(acc[ 4+j][0]));
      const float gv = 2.0f*frcp(1.0f + fexp2(acc[ 8+j][0])) - 1.0f;
      const float ov = frcp(1.0f + fexp2(acc[12+j][0]));
      const float cc = fv*cst[j] + iv*gv;
      cst[j] = cc;
      const float r = frcp(1.0f + fexp2(cc*(-2.0f*L2E)));
      hval[j] = 2.0f*ov*r - ov;
    }

    // publish h_t: lanes 0-15 write unit 16j+ln as f16 (4 ds_write_b16)
    if (l < 16){
      unsigned short* hs = reinterpret_cast<unsigned short*>(hlds);
      #pragma unroll
      for (int j = 0; j < 4; ++j)
        hs[16*j + ln] = __builtin_bit_cast(unsigned short, (_Float16)hval[j]);
    }
  }

  if (l < 16){
    // final h: lanes 0-15 hold units 16j+ln
    float hv[4];
    {
      const unsigned short* hs = reinterpret_cast<const unsigned short*>(hlds);
      #pragma unroll
      for (int j = 0; j < 4; ++j)
        hv[j] = (float)__builtin_bit_cast(_Float16, hs[16*j + ln]);
    }
    #pragma unroll
    for (int j = 0; j < 4; ++j)
      hout[b*HH + 16*j + ln] = hv[j];
  }
}

// Backward direction contributes only ONE step (scan reverse=True: output at
// t=T-1 is the first reverse step from zero state => W_hh_b unused, c = i*g).
// Fused with the final linear layer.
__global__ __launch_bounds__(64, 1) void lstm_bwd_lin_kernel(
    const float* __restrict__ x,   const float* __restrict__ Wib,
    const float* __restrict__ bib, const float* __restrict__ bhb,
    const float* __restrict__ Wlin,const float* __restrict__ blin,
    const float* __restrict__ hf,  float* __restrict__ out)
{
  const int b = blockIdx.x;
  const int j = threadIdx.x;  // 0..63
  const float* xt = x + ((size_t)b*TT + (TT-1))*7;
  float xv[7];
  #pragma unroll
  for (int k = 0; k < 7; k++) xv[k] = xt[k];

  float g4[4];
  #pragma unroll
  for (int qq = 0; qq < 4; qq++){
    const int g = qq*HH + j;
    float a = bib[g] + bhb[g];
    #pragma unroll
    for (int k = 0; k < 7; k++) a += xv[k]*Wib[g*7+k];
    g4[qq] = a;
  }
  const float iv = fsig(g4[0]);
  const float gv = ftanh(g4[2]);
  const float ov = fsig(g4[3]);
  const float cc = iv*gv;          // f * c0 = 0
  const float hb = ov*ftanh(cc);
  const float hfv = hf[b*HH + j];

  float s[3];
  #pragma unroll
  for (int o = 0; o < 3; o++)
    s[o] = hfv*Wlin[o*128 + j] + hb*Wlin[o*128 + 64 + j];

  #pragma unroll
  for (int o = 0; o < 3; o++){
    float v = s[o];
    #pragma unroll
    for (int m = 32; m >= 1; m >>= 1) v += __shfl_xor(v, m, 64);
    s[o] = v;
  }
  if (j == 0){
    out[b*3+0] = s[0] + blin[0];
    out[b*3+1] = s[1] + blin[1];
    out[b*3+2] = s[2] + blin[2];
  }
}

extern "C" void kernel_launch(void* const* d_in, const int* in_sizes, int n_in,
                              void* d_out, int out_size, void* d_ws, size_t ws_size,
                              hipStream_t stream)
{
  const float* x    = (const float*)d_in[0];
  const float* Wihf = (const float*)d_in[1];
  const float* Whhf = (const float*)d_in[2];
  const float* bihf = (const float*)d_in[3];
  const float* bhhf = (const float*)d_in[4];
  const float* Wihb = (const float*)d_in[5];
  // d_in[6] (W_hh_b) is mathematically unused: backward state starts at zero
  const float* bibb = (const float*)d_in[7];
  const float* bhbb = (const float*)d_in[8];
  const float* Wlin = (const float*)d_in[9];
  const float* blin = (const float*)d_in[10];
  float* out = (float*)d_out;
  float* hf  = (float*)d_ws;   // [512,64] fp32 scratch

  lstm_fwd_kernel<<<BB, 64, 0, stream>>>(x, Wihf, Whhf, bihf, bhhf, hf);
  lstm_bwd_lin_kernel<<<BB, 64, 0, stream>>>(x, Wihb, bibb, bhbb, Wlin, blin, hf, out);
}